// Round 1
// 1447.130 us; speedup vs baseline: 1.7593x; 1.7593x over previous
//
#include <hip/hip_runtime.h>
#include <cstdint>
#include <cstddef>

// ---------------- problem constants ----------------
#define NLAYER 4
#define CDIM   512
#define TLEN   1024
#define BSZ    2
#define MROWS  (BSZ * TLEN)   // 2048
#define VOCAB  50257
#define NHEAD  8
#define HDIM   64
#define LORA_S 4.0f

typedef unsigned short ushort_t;
typedef __attribute__((ext_vector_type(8))) short  short8;
typedef __attribute__((ext_vector_type(8))) _Float16 half8;
typedef __attribute__((ext_vector_type(4))) float  f32x4;
typedef __attribute__((ext_vector_type(4))) unsigned short us4;

// fp32 -> bf16, round-to-nearest-even (finite inputs only)
__device__ inline ushort_t f2bf(float f) {
  union { float f; unsigned u; } c; c.f = f;
  unsigned u = c.u;
  u += 0x7fffu + ((u >> 16) & 1u);
  return (ushort_t)(u >> 16);
}

// fp32 -> fp16 bits (native v_cvt_f16_f32)
__device__ inline ushort_t f2h(float f) {
  union { _Float16 h; ushort_t u; } c; c.h = (_Float16)f;
  return c.u;
}

// async global->LDS, 16B per lane; lds dest = wave-uniform base + lane*16
__device__ inline void stage16(const ushort_t* g, ushort_t* lds) {
  __builtin_amdgcn_global_load_lds(
      (__attribute__((address_space(1))) unsigned int*)(g),
      (__attribute__((address_space(3))) unsigned int*)(lds),
      16, 0, 0);
}

// ---------------- bf16 MFMA GEMM:  C[M,N] = A[M,K] @ B[N,K]^T  (fp32 out) ----
// 128x128 block tile, BK=32, 4 waves each computing a 64x64 subtile (4x4 MFMA).
// M must be a multiple of 128; N guarded (head matmul N=50257); K multiple of 32.
__global__ __launch_bounds__(256) void gemm_bt(const ushort_t* __restrict__ A,
                                               const ushort_t* __restrict__ B,
                                               float* __restrict__ C,
                                               int M, int N, int K) {
  __shared__ ushort_t As[128 * 32];   // 8 KB, row-major [row][k]
  __shared__ ushort_t Bs[128 * 32];   // 8 KB, row-major [n][k]
  const int tid  = threadIdx.x;
  const int wave = tid >> 6, lane = tid & 63;
  const int m0 = blockIdx.y << 7;
  const int n0 = blockIdx.x << 7;
  const int wr = (wave >> 1) << 6;    // wave sub-tile row base (0/64)
  const int wc = (wave & 1) << 6;     // wave sub-tile col base (0/64)
  const int lr = lane & 15;           // fragment row
  const int kq = (lane >> 4) << 3;    // fragment k offset (quad*8)

  f32x4 acc[4][4];
#pragma unroll
  for (int i = 0; i < 4; ++i)
#pragma unroll
    for (int j = 0; j < 4; ++j) {
      acc[i][j][0] = 0.f; acc[i][j][1] = 0.f;
      acc[i][j][2] = 0.f; acc[i][j][3] = 0.f;
    }

  for (int k0 = 0; k0 < K; k0 += 32) {
    __syncthreads();   // protect LDS from previous iteration's readers
    // A tile: 128x32 bf16 = 512 chunks of 16B; thread t stages chunks t, t+256
#pragma unroll
    for (int i = 0; i < 2; ++i) {
      int c = i * 256 + tid;
      int row = c >> 2, col = (c & 3) << 3;
      stage16(A + (size_t)(m0 + row) * K + k0 + col,
              As + ((i * 256 + (wave << 6)) << 3));
    }
#pragma unroll
    for (int i = 0; i < 2; ++i) {
      int c = i * 256 + tid;
      int row = c >> 2, col = (c & 3) << 3;
      int n = n0 + row; if (n > N - 1) n = N - 1;   // clamp (head tail tile)
      stage16(B + (size_t)n * K + k0 + col,
              Bs + ((i * 256 + (wave << 6)) << 3));
    }
    __syncthreads();   // drains vmcnt -> LDS tiles ready

    short8 af[4], bf[4];
#pragma unroll
    for (int i = 0; i < 4; ++i)
      af[i] = *(const short8*)(As + (wr + i * 16 + lr) * 32 + kq);
#pragma unroll
    for (int j = 0; j < 4; ++j)
      bf[j] = *(const short8*)(Bs + (wc + j * 16 + lr) * 32 + kq);
#pragma unroll
    for (int i = 0; i < 4; ++i)
#pragma unroll
      for (int j = 0; j < 4; ++j)
        acc[i][j] = __builtin_amdgcn_mfma_f32_16x16x32_bf16(af[i], bf[j], acc[i][j], 0, 0, 0);
  }

  // epilogue: D mapping col=lane&15, row=(lane>>4)*4+reg
  const int rq = (lane >> 4) << 2;
  const int cl = lane & 15;
#pragma unroll
  for (int i = 0; i < 4; ++i) {
    int mb = m0 + wr + i * 16 + rq;
#pragma unroll
    for (int j = 0; j < 4; ++j) {
      int col = n0 + wc + j * 16 + cl;
      if (col < N) {
        float* cp = C + (size_t)mb * N + col;
#pragma unroll
        for (int r = 0; r < 4; ++r) cp[(size_t)r * N] = acc[i][j][r];
      }
    }
  }
}

// ---------------- weight prep ----------------
// plain fp32 -> bf16 (vectorized x4)
__global__ void conv_bf16(const float* __restrict__ in, ushort_t* __restrict__ out, long n) {
  long i = ((long)blockIdx.x * 256 + threadIdx.x) * 4;
  if (i < n) {
    float4 v = *(const float4*)(in + i);
    us4 o = { f2bf(v.x), f2bf(v.y), f2bf(v.z), f2bf(v.w) };
    *(us4*)(out + i) = o;
  }
}

// W'[l][n][k] = bf16( W + LORA_S * lB[l][n][:8] . lA[l][:8][k] ), K = 512
__global__ void conv_lora(const float* __restrict__ W, const float* __restrict__ lA,
                          const float* __restrict__ lB, ushort_t* __restrict__ out,
                          int N, long total) {
  long i = (long)blockIdx.x * 256 + threadIdx.x;
  if (i >= total) return;
  long nk = (long)N * CDIM;
  int  l  = (int)(i / nk);
  long r  = i - (long)l * nk;
  int  n  = (int)(r >> 9);
  int  k  = (int)(r & 511);
  const float* lAp = lA + (long)l * 8 * CDIM;
  const float* lBp = lB + (long)l * N * 8;
  float acc = W[i];
#pragma unroll
  for (int j = 0; j < 8; ++j) acc += LORA_S * lBp[n * 8 + j] * lAp[j * CDIM + k];
  out[i] = f2bf(acc);
}

// ---------------- embedding ----------------
__global__ void embed_kernel(const int* __restrict__ idx, const float* __restrict__ wte,
                             const float* __restrict__ wpe, float* __restrict__ x) {
  int i = blockIdx.x * 256 + threadIdx.x;   // over MROWS*CDIM = 1M
  int m = i >> 9, c = i & 511;
  int t = m & (TLEN - 1);
  x[i] = wte[(size_t)idx[m] * CDIM + c] + wpe[(size_t)t * CDIM + c];
}

// ---------------- layernorm (fp32 in, bf16 out), one row per block ----------
__global__ __launch_bounds__(256) void ln_kernel(const float* __restrict__ x,
                                                 const float* __restrict__ g,
                                                 const float* __restrict__ b,
                                                 ushort_t* __restrict__ out) {
  const int m = blockIdx.x, tid = threadIdx.x;
  const float2 v = ((const float2*)(x + (size_t)m * CDIM))[tid];
  float s = v.x + v.y, ss = v.x * v.x + v.y * v.y;
#pragma unroll
  for (int off = 32; off; off >>= 1) { s += __shfl_xor(s, off); ss += __shfl_xor(ss, off); }
  __shared__ float rs[4], rss[4];
  const int w = tid >> 6, lane = tid & 63;
  if (lane == 0) { rs[w] = s; rss[w] = ss; }
  __syncthreads();
  s  = rs[0] + rs[1] + rs[2] + rs[3];
  ss = rss[0] + rss[1] + rss[2] + rss[3];
  const float mean = s * (1.f / CDIM);
  const float var  = ss * (1.f / CDIM) - mean * mean;
  const float rstd = rsqrtf(var + 1e-5f);
  const int c = tid * 2;
  out[(size_t)m * CDIM + c]     = f2bf((v.x - mean) * rstd * g[c]     + b[c]);
  out[(size_t)m * CDIM + c + 1] = f2bf((v.y - mean) * rstd * g[c + 1] + b[c + 1]);
}

// ---------------- flash attention, fp16 MFMA, causal ------------------------
// grid (TLEN/64, BSZ*NHEAD), block 256 (4 waves).
// Each wave owns 16 q rows (one 16x16x32 A-fragment set, Q in registers).
// K-loop over 32-key tiles staged in LDS by all 4 waves:
//   K row-major [32][72 pad]  (stride 72 halves = 144B -> 2-way/free b128 reads)
//   V transposed [64][40 pad] (stride 40 halves = 80B  -> 2-way/free b128 reads)
// Online softmax in fragment layout (q on (lane>>4)*4+reg, k on lane&15);
// P round-trips per-wave LDS buffer to become the PV A-fragment.
// Output written directly as bf16 (feeds proj GEMM).
__global__ __launch_bounds__(256) void attn_mfma(const float* __restrict__ qkv,
                                                 ushort_t* __restrict__ ybf) {
  __shared__ ushort_t Ks[32 * 72];      // 4.5 KB
  __shared__ ushort_t Vt[64 * 40];      // 5.0 KB
  __shared__ ushort_t Pl[4 * 16 * 40];  // 5.0 KB (per-wave 16x32 P, stride 40)

  const int tid  = threadIdx.x;
  const int wave = tid >> 6, lane = tid & 63;
  const int lr   = lane & 15;           // fragment row / output col
  const int quad = lane >> 4;
  const int kq   = quad << 3;           // fragment k offset
  const int t0   = blockIdx.x << 6;     // block q base (64 rows)
  const int bh   = blockIdx.y;
  const int bb   = bh >> 3, hh = bh & 7;
  const int qb   = t0 + (wave << 4);    // wave q base (16 rows)
  const size_t RS = 3 * CDIM;           // 1536

  // --- Q fragments: A[q=16][d=64] as 2 chunks of K=32 ---
  half8 aq[2];
  {
    const float* qr = qkv + (size_t)(bb * TLEN + qb + lr) * RS + hh * 64 + kq;
#pragma unroll
    for (int c = 0; c < 2; ++c) {
      float4 f0 = *(const float4*)(qr + c * 32);
      float4 f1 = *(const float4*)(qr + c * 32 + 4);
      half8 v;
      v[0] = (_Float16)f0.x; v[1] = (_Float16)f0.y;
      v[2] = (_Float16)f0.z; v[3] = (_Float16)f0.w;
      v[4] = (_Float16)f1.x; v[5] = (_Float16)f1.y;
      v[6] = (_Float16)f1.z; v[7] = (_Float16)f1.w;
      aq[c] = v;
    }
  }

  f32x4 o[4];
#pragma unroll
  for (int dt = 0; dt < 4; ++dt) { o[dt][0] = 0.f; o[dt][1] = 0.f; o[dt][2] = 0.f; o[dt][3] = 0.f; }
  float m[4] = { -1e30f, -1e30f, -1e30f, -1e30f };
  float l[4] = { 0.f, 0.f, 0.f, 0.f };

  // staging decomposition: thread -> (key kk, d-chunk of 8)
  const int kk    = tid & 31;
  const int dbase = (tid >> 5) << 3;

  const int ntiles = (blockIdx.x + 1) << 1;   // causal: keys 0 .. t0+63
  for (int kb = 0; kb < ntiles; ++kb) {
    const int kbase = kb << 5;
    __syncthreads();   // protect LDS from previous iteration's readers
    {
      const float* kp = qkv + (size_t)(bb * TLEN + kbase + kk) * RS + CDIM + hh * 64 + dbase;
      float4 f0 = *(const float4*)kp;
      float4 f1 = *(const float4*)(kp + 4);
      half8 kv;
      kv[0] = (_Float16)f0.x; kv[1] = (_Float16)f0.y;
      kv[2] = (_Float16)f0.z; kv[3] = (_Float16)f0.w;
      kv[4] = (_Float16)f1.x; kv[5] = (_Float16)f1.y;
      kv[6] = (_Float16)f1.z; kv[7] = (_Float16)f1.w;
      *(half8*)(Ks + kk * 72 + dbase) = kv;
      const float* vp = kp + CDIM;          // V block
      float4 g0 = *(const float4*)vp;
      float4 g1 = *(const float4*)(vp + 4);
      ushort_t vb[8] = { f2h(g0.x), f2h(g0.y), f2h(g0.z), f2h(g0.w),
                         f2h(g1.x), f2h(g1.y), f2h(g1.z), f2h(g1.w) };
#pragma unroll
      for (int j = 0; j < 8; ++j) Vt[(dbase + j) * 40 + kk] = vb[j];  // transpose
    }
    __syncthreads();   // tiles ready

    if (kbase <= qb + 15) {   // wave-uniform causal skip
      // --- S = Q @ K^T : two 16x16 k-sub-tiles ---
      f32x4 st[2];
#pragma unroll
      for (int kt = 0; kt < 2; ++kt) {
        half8 b0 = *(const half8*)(Ks + (kt * 16 + lr) * 72 + kq);
        half8 b1 = *(const half8*)(Ks + (kt * 16 + lr) * 72 + 32 + kq);
        f32x4 acc = { 0.f, 0.f, 0.f, 0.f };
        acc = __builtin_amdgcn_mfma_f32_16x16x32_f16(aq[0], b0, acc, 0, 0, 0);
        acc = __builtin_amdgcn_mfma_f32_16x16x32_f16(aq[1], b1, acc, 0, 0, 0);
        st[kt] = acc;
      }
      // --- scale + causal mask + online softmax ---
      float corr[4];
#pragma unroll
      for (int r = 0; r < 4; ++r) {
        const int qrow = qb + quad * 4 + r;
#pragma unroll
        for (int kt = 0; kt < 2; ++kt) {
          const int kcol = kbase + kt * 16 + lr;
          float s = st[kt][r] * 0.125f;           // 1/sqrt(64)
          st[kt][r] = (kcol <= qrow) ? s : -1e30f;
        }
        float mx = fmaxf(st[0][r], st[1][r]);
#pragma unroll
        for (int off = 8; off; off >>= 1) mx = fmaxf(mx, __shfl_xor(mx, off));
        const float mnew = fmaxf(m[r], mx);
        corr[r] = __expf(m[r] - mnew);
        m[r] = mnew;
        float p0 = __expf(st[0][r] - mnew);
        float p1 = __expf(st[1][r] - mnew);
        st[0][r] = p0; st[1][r] = p1;
        float ps = p0 + p1;
#pragma unroll
        for (int off = 8; off; off >>= 1) ps += __shfl_xor(ps, off);
        l[r] = l[r] * corr[r] + ps;
      }
      // --- rescale O, stash P (fp16) to per-wave LDS, PV MFMA ---
#pragma unroll
      for (int dt = 0; dt < 4; ++dt)
#pragma unroll
        for (int r = 0; r < 4; ++r) o[dt][r] *= corr[r];
      ushort_t* pw = Pl + wave * 640;   // 16 rows x 40
#pragma unroll
      for (int kt = 0; kt < 2; ++kt)
#pragma unroll
        for (int r = 0; r < 4; ++r)
          pw[(quad * 4 + r) * 40 + kt * 16 + lr] = f2h(st[kt][r]);
      half8 ap = *(const half8*)(pw + lr * 40 + kq);   // A[q=16][k=32] fragment
#pragma unroll
      for (int dt = 0; dt < 4; ++dt) {
        half8 bv = *(const half8*)(Vt + (dt * 16 + lr) * 40 + kq);
        o[dt] = __builtin_amdgcn_mfma_f32_16x16x32_f16(ap, bv, o[dt], 0, 0, 0);
      }
    }
  }

  // --- epilogue: normalize, write bf16 directly ---
#pragma unroll
  for (int r = 0; r < 4; ++r) {
    const float inv = 1.0f / l[r];
    const int qrow = qb + quad * 4 + r;
    ushort_t* yp = ybf + (size_t)(bb * TLEN + qrow) * CDIM + hh * 64;
#pragma unroll
    for (int dt = 0; dt < 4; ++dt)
      yp[dt * 16 + lr] = f2bf(o[dt][r] * inv);
  }
}

// ---------------- elementwise ----------------
// x += delta (+ bias per col, cols=512); n = MROWS*CDIM
__global__ void add_res(float* __restrict__ x, const float* __restrict__ d,
                        const float* __restrict__ bias, int n) {
  int i = blockIdx.x * 256 + threadIdx.x;
  if (i < n) {
    float v = x[i] + d[i];
    if (bias) v += bias[i & 511];
    x[i] = v;
  }
}

// out = bf16(gelu(in + bias[col])), cols = 2048
__global__ void gelu_bias(const float* __restrict__ in, const float* __restrict__ bias,
                          ushort_t* __restrict__ out, int n) {
  int i = blockIdx.x * 256 + threadIdx.x;
  if (i < n) {
    float v = in[i] + bias[i & 2047];
    float t = tanhf(0.7978845608028654f * (v + 0.044715f * v * v * v));
    out[i] = f2bf(0.5f * v * (1.0f + t));
  }
}

// ---------------- launch ----------------
extern "C" void kernel_launch(void* const* d_in, const int* in_sizes, int n_in,
                              void* d_out, int out_size, void* d_ws, size_t ws_size,
                              hipStream_t stream) {
  const int*   idx     = (const int*)  d_in[0];
  const float* wte     = (const float*)d_in[1];
  const float* wpe     = (const float*)d_in[2];
  const float* ln1_g   = (const float*)d_in[3];
  const float* ln1_b   = (const float*)d_in[4];
  const float* attn_w  = (const float*)d_in[5];
  const float* attn_lA = (const float*)d_in[6];
  const float* attn_lB = (const float*)d_in[7];
  const float* proj_w  = (const float*)d_in[8];
  const float* proj_lA = (const float*)d_in[9];
  const float* proj_lB = (const float*)d_in[10];
  const float* ln2_g   = (const float*)d_in[11];
  const float* ln2_b   = (const float*)d_in[12];
  const float* fc_w    = (const float*)d_in[13];
  const float* fc_b    = (const float*)d_in[14];
  const float* mproj_w = (const float*)d_in[15];
  const float* mproj_b = (const float*)d_in[16];
  const float* lnf_g   = (const float*)d_in[17];
  const float* lnf_b   = (const float*)d_in[18];
  const float* head_w  = (const float*)d_in[19];
  float* out = (float*)d_out;

  // workspace carve (256B aligned)
  uintptr_t p = (uintptr_t)d_ws;
  auto take = [&](size_t bytes) -> void* {
    uintptr_t q = p;
    p = (p + bytes + 255) & ~(uintptr_t)255;
    return (void*)q;
  };
  ushort_t* wAttnB  = (ushort_t*)take((size_t)NLAYER * 1536 * 512 * 2);
  ushort_t* wProjB  = (ushort_t*)take((size_t)NLAYER * 512 * 512 * 2);
  ushort_t* wFcB    = (ushort_t*)take((size_t)NLAYER * 2048 * 512 * 2);
  ushort_t* wMprojB = (ushort_t*)take((size_t)NLAYER * 512 * 2048 * 2);
  ushort_t* wHeadB  = (ushort_t*)take((size_t)VOCAB * 512 * 2);
  float*    x       = (float*)   take((size_t)MROWS * 512 * 4);
  ushort_t* hbf     = (ushort_t*)take((size_t)MROWS * 512 * 2);
  float*    qkv     = (float*)   take((size_t)MROWS * 1536 * 4);
  ushort_t* ybf     = (ushort_t*)take((size_t)MROWS * 512 * 2);
  float*    tmp     = (float*)   take((size_t)MROWS * 512 * 4);
  float*    fcf     = (float*)   take((size_t)MROWS * 2048 * 4);
  ushort_t* mbf     = (ushort_t*)take((size_t)MROWS * 2048 * 2);

  // ---- weight prep (per launch; LoRA folded into qkv/proj weights) ----
  {
    long nA = (long)NLAYER * 1536 * 512;
    conv_lora<<<(int)((nA + 255) / 256), 256, 0, stream>>>(attn_w, attn_lA, attn_lB, wAttnB, 1536, nA);
    long nP = (long)NLAYER * 512 * 512;
    conv_lora<<<(int)((nP + 255) / 256), 256, 0, stream>>>(proj_w, proj_lA, proj_lB, wProjB, 512, nP);
    long nF = (long)NLAYER * 2048 * 512;
    conv_bf16<<<(int)((nF / 4 + 255) / 256), 256, 0, stream>>>(fc_w, wFcB, nF);
    long nM = (long)NLAYER * 512 * 2048;
    conv_bf16<<<(int)((nM / 4 + 255) / 256), 256, 0, stream>>>(mproj_w, wMprojB, nM);
    long nH = (long)VOCAB * 512;
    conv_bf16<<<(int)((nH / 4 + 255) / 256), 256, 0, stream>>>(head_w, wHeadB, nH);
  }

  // ---- embedding ----
  embed_kernel<<<(MROWS * 512) / 256, 256, 0, stream>>>(idx, wte, wpe, x);

  // ---- transformer layers ----
  for (int l = 0; l < NLAYER; ++l) {
    ln_kernel<<<MROWS, 256, 0, stream>>>(x, ln1_g + l * 512, ln1_b + l * 512, hbf);
    gemm_bt<<<dim3(1536 / 128, MROWS / 128), 256, 0, stream>>>(
        hbf, wAttnB + (size_t)l * 1536 * 512, qkv, MROWS, 1536, 512);
    attn_mfma<<<dim3(TLEN / 64, BSZ * NHEAD), 256, 0, stream>>>(qkv, ybf);
    gemm_bt<<<dim3(512 / 128, MROWS / 128), 256, 0, stream>>>(
        ybf, wProjB + (size_t)l * 512 * 512, tmp, MROWS, 512, 512);
    add_res<<<(MROWS * 512) / 256, 256, 0, stream>>>(x, tmp, nullptr, MROWS * 512);

    ln_kernel<<<MROWS, 256, 0, stream>>>(x, ln2_g + l * 512, ln2_b + l * 512, hbf);
    gemm_bt<<<dim3(2048 / 128, MROWS / 128), 256, 0, stream>>>(
        hbf, wFcB + (size_t)l * 2048 * 512, fcf, MROWS, 2048, 512);
    gelu_bias<<<(MROWS * 2048) / 256, 256, 0, stream>>>(fcf, fc_b + l * 2048, mbf, MROWS * 2048);
    gemm_bt<<<dim3(512 / 128, MROWS / 128), 256, 0, stream>>>(
        mbf, wMprojB + (size_t)l * 512 * 2048, tmp, MROWS, 512, 2048);
    add_res<<<(MROWS * 512) / 256, 256, 0, stream>>>(x, tmp, mproj_b + l * 512, MROWS * 512);
  }

  // ---- final LN + head ----
  ln_kernel<<<MROWS, 256, 0, stream>>>(x, lnf_g, lnf_b, hbf);
  gemm_bt<<<dim3((VOCAB + 127) / 128, MROWS / 128), 256, 0, stream>>>(
      hbf, wHeadB, out, MROWS, VOCAB, 512);
}

// Round 2
// 1337.271 us; speedup vs baseline: 1.9038x; 1.0822x over previous
//
#include <hip/hip_runtime.h>
#include <cstdint>
#include <cstddef>

// ---------------- problem constants ----------------
#define NLAYER 4
#define CDIM   512
#define TLEN   1024
#define BSZ    2
#define MROWS  (BSZ * TLEN)   // 2048
#define VOCAB  50257
#define NHEAD  8
#define HDIM   64
#define LORA_S 4.0f

typedef unsigned short ushort_t;
typedef __attribute__((ext_vector_type(8))) short  short8;
typedef __attribute__((ext_vector_type(8))) _Float16 half8;
typedef __attribute__((ext_vector_type(4))) float  f32x4;
typedef __attribute__((ext_vector_type(4))) unsigned short us4;

// fp32 -> bf16, round-to-nearest-even (finite inputs only)
__device__ inline ushort_t f2bf(float f) {
  union { float f; unsigned u; } c; c.f = f;
  unsigned u = c.u;
  u += 0x7fffu + ((u >> 16) & 1u);
  return (ushort_t)(u >> 16);
}

// fp32 -> fp16 bits (native v_cvt_f16_f32)
__device__ inline ushort_t f2h(float f) {
  union { _Float16 h; ushort_t u; } c; c.h = (_Float16)f;
  return c.u;
}

__device__ inline float gelu_f(float v) {
  float t = tanhf(0.7978845608028654f * (v + 0.044715f * v * v * v));
  return 0.5f * v * (1.0f + t);
}

// async global->LDS, 16B per lane; lds dest = wave-uniform base + lane*16
__device__ inline void stage16(const ushort_t* g, ushort_t* lds) {
  __builtin_amdgcn_global_load_lds(
      (__attribute__((address_space(1))) unsigned int*)(g),
      (__attribute__((address_space(3))) unsigned int*)(lds),
      16, 0, 0);
}

// ---------------- bf16 MFMA GEMM:  C[M,N] = A[M,K] @ B[N,K]^T ----------------
// 128x128 block tile, BK=32, 4 waves each computing a 64x64 subtile (4x4 MFMA).
// M multiple of 128; N guarded (head matmul N=50257); K multiple of 32.
// EPI: 0 = plain fp32 store; 2 = bf16 store of gelu(acc + bias[col]).
template<int EPI>
__global__ __launch_bounds__(256) void gemm_bt(const ushort_t* __restrict__ A,
                                               const ushort_t* __restrict__ B,
                                               void* __restrict__ Cv,
                                               const float* __restrict__ bias,
                                               int M, int N, int K) {
  __shared__ ushort_t As[128 * 32];   // 8 KB, row-major [row][k]
  __shared__ ushort_t Bs[128 * 32];   // 8 KB, row-major [n][k]
  const int tid  = threadIdx.x;
  const int wave = tid >> 6, lane = tid & 63;
  const int m0 = blockIdx.y << 7;
  const int n0 = blockIdx.x << 7;
  const int wr = (wave >> 1) << 6;    // wave sub-tile row base (0/64)
  const int wc = (wave & 1) << 6;     // wave sub-tile col base (0/64)
  const int lr = lane & 15;           // fragment row
  const int kq = (lane >> 4) << 3;    // fragment k offset (quad*8)

  f32x4 acc[4][4];
#pragma unroll
  for (int i = 0; i < 4; ++i)
#pragma unroll
    for (int j = 0; j < 4; ++j) {
      acc[i][j][0] = 0.f; acc[i][j][1] = 0.f;
      acc[i][j][2] = 0.f; acc[i][j][3] = 0.f;
    }

  for (int k0 = 0; k0 < K; k0 += 32) {
    __syncthreads();   // protect LDS from previous iteration's readers
    // A tile: 128x32 bf16 = 512 chunks of 16B; thread t stages chunks t, t+256
#pragma unroll
    for (int i = 0; i < 2; ++i) {
      int c = i * 256 + tid;
      int row = c >> 2, col = (c & 3) << 3;
      stage16(A + (size_t)(m0 + row) * K + k0 + col,
              As + ((i * 256 + (wave << 6)) << 3));
    }
#pragma unroll
    for (int i = 0; i < 2; ++i) {
      int c = i * 256 + tid;
      int row = c >> 2, col = (c & 3) << 3;
      int n = n0 + row; if (n > N - 1) n = N - 1;   // clamp (head tail tile)
      stage16(B + (size_t)n * K + k0 + col,
              Bs + ((i * 256 + (wave << 6)) << 3));
    }
    __syncthreads();   // drains vmcnt -> LDS tiles ready

    short8 af[4], bf[4];
#pragma unroll
    for (int i = 0; i < 4; ++i)
      af[i] = *(const short8*)(As + (wr + i * 16 + lr) * 32 + kq);
#pragma unroll
    for (int j = 0; j < 4; ++j)
      bf[j] = *(const short8*)(Bs + (wc + j * 16 + lr) * 32 + kq);
#pragma unroll
    for (int i = 0; i < 4; ++i)
#pragma unroll
      for (int j = 0; j < 4; ++j)
        acc[i][j] = __builtin_amdgcn_mfma_f32_16x16x32_bf16(af[i], bf[j], acc[i][j], 0, 0, 0);
  }

  // epilogue: D mapping col=lane&15, row=(lane>>4)*4+reg
  const int rq = (lane >> 4) << 2;
  const int cl = lane & 15;
#pragma unroll
  for (int i = 0; i < 4; ++i) {
    int mb = m0 + wr + i * 16 + rq;
#pragma unroll
    for (int j = 0; j < 4; ++j) {
      int col = n0 + wc + j * 16 + cl;
      if (col < N) {
        if (EPI == 0) {
          float* cp = (float*)Cv + (size_t)mb * N + col;
#pragma unroll
          for (int r = 0; r < 4; ++r) cp[(size_t)r * N] = acc[i][j][r];
        } else {
          ushort_t* cp = (ushort_t*)Cv + (size_t)mb * N + col;
          const float bb = bias[col];
#pragma unroll
          for (int r = 0; r < 4; ++r) cp[(size_t)r * N] = f2bf(gelu_f(acc[i][j][r] + bb));
        }
      }
    }
  }
}

// ---------------- 64x64-tile GEMM with fused residual: x += A@B^T (+bias) ---
// grid (N/64, M/64), 256 threads (4 waves, each a 32x32 subtile). BK=32.
__global__ __launch_bounds__(256) void gemm64_res(const ushort_t* __restrict__ A,
                                                  const ushort_t* __restrict__ B,
                                                  float* __restrict__ x,
                                                  const float* __restrict__ bias,
                                                  int M, int N, int K) {
  __shared__ ushort_t As[64 * 32];   // 4 KB
  __shared__ ushort_t Bs[64 * 32];   // 4 KB
  const int tid  = threadIdx.x;
  const int wave = tid >> 6, lane = tid & 63;
  const int m0 = blockIdx.y << 6;
  const int n0 = blockIdx.x << 6;
  const int wr = (wave >> 1) << 5;    // 0/32
  const int wc = (wave & 1) << 5;     // 0/32
  const int lr = lane & 15;
  const int kq = (lane >> 4) << 3;

  f32x4 acc[2][2];
#pragma unroll
  for (int i = 0; i < 2; ++i)
#pragma unroll
    for (int j = 0; j < 2; ++j) {
      acc[i][j][0] = 0.f; acc[i][j][1] = 0.f;
      acc[i][j][2] = 0.f; acc[i][j][3] = 0.f;
    }

  // staging: 64x32 tile = 256 chunks of 16B; thread t stages chunk t
  const int row = tid >> 2, col = (tid & 3) << 3;

  for (int k0 = 0; k0 < K; k0 += 32) {
    __syncthreads();
    stage16(A + (size_t)(m0 + row) * K + k0 + col, As + (wave << 9));
    stage16(B + (size_t)(n0 + row) * K + k0 + col, Bs + (wave << 9));
    __syncthreads();

    short8 af[2], bf[2];
#pragma unroll
    for (int i = 0; i < 2; ++i)
      af[i] = *(const short8*)(As + (wr + i * 16 + lr) * 32 + kq);
#pragma unroll
    for (int j = 0; j < 2; ++j)
      bf[j] = *(const short8*)(Bs + (wc + j * 16 + lr) * 32 + kq);
#pragma unroll
    for (int i = 0; i < 2; ++i)
#pragma unroll
      for (int j = 0; j < 2; ++j)
        acc[i][j] = __builtin_amdgcn_mfma_f32_16x16x32_bf16(af[i], bf[j], acc[i][j], 0, 0, 0);
  }

  const int rq = (lane >> 4) << 2;
  const int cl = lane & 15;
#pragma unroll
  for (int i = 0; i < 2; ++i) {
    int mb = m0 + wr + i * 16 + rq;
#pragma unroll
    for (int j = 0; j < 2; ++j) {
      int c = n0 + wc + j * 16 + cl;
      float bb = bias ? bias[c] : 0.f;
      float* xp = x + (size_t)mb * N + c;
#pragma unroll
      for (int r = 0; r < 4; ++r) xp[(size_t)r * N] = xp[(size_t)r * N] + acc[i][j][r] + bb;
    }
  }
}

// ---------------- weight prep ----------------
// plain fp32 -> bf16 (vectorized x4)
__global__ void conv_bf16(const float* __restrict__ in, ushort_t* __restrict__ out, long n) {
  long i = ((long)blockIdx.x * 256 + threadIdx.x) * 4;
  if (i < n) {
    float4 v = *(const float4*)(in + i);
    us4 o = { f2bf(v.x), f2bf(v.y), f2bf(v.z), f2bf(v.w) };
    *(us4*)(out + i) = o;
  }
}

// W'[l][n][k] = bf16( W + LORA_S * lB[l][n][:8] . lA[l][:8][k] ), K = 512
__global__ void conv_lora(const float* __restrict__ W, const float* __restrict__ lA,
                          const float* __restrict__ lB, ushort_t* __restrict__ out,
                          int N, long total) {
  long i = (long)blockIdx.x * 256 + threadIdx.x;
  if (i >= total) return;
  long nk = (long)N * CDIM;
  int  l  = (int)(i / nk);
  long r  = i - (long)l * nk;
  int  n  = (int)(r >> 9);
  int  k  = (int)(r & 511);
  const float* lAp = lA + (long)l * 8 * CDIM;
  const float* lBp = lB + (long)l * N * 8;
  float acc = W[i];
#pragma unroll
  for (int j = 0; j < 8; ++j) acc += LORA_S * lBp[n * 8 + j] * lAp[j * CDIM + k];
  out[i] = f2bf(acc);
}

// ---------------- embedding ----------------
__global__ void embed_kernel(const int* __restrict__ idx, const float* __restrict__ wte,
                             const float* __restrict__ wpe, float* __restrict__ x) {
  int i = blockIdx.x * 256 + threadIdx.x;   // over MROWS*CDIM = 1M
  int m = i >> 9, c = i & 511;
  int t = m & (TLEN - 1);
  x[i] = wte[(size_t)idx[m] * CDIM + c] + wpe[(size_t)t * CDIM + c];
}

// ---------------- layernorm (fp32 in, bf16 out), one row per block ----------
__global__ __launch_bounds__(256) void ln_kernel(const float* __restrict__ x,
                                                 const float* __restrict__ g,
                                                 const float* __restrict__ b,
                                                 ushort_t* __restrict__ out) {
  const int m = blockIdx.x, tid = threadIdx.x;
  const float2 v = ((const float2*)(x + (size_t)m * CDIM))[tid];
  float s = v.x + v.y, ss = v.x * v.x + v.y * v.y;
#pragma unroll
  for (int off = 32; off; off >>= 1) { s += __shfl_xor(s, off); ss += __shfl_xor(ss, off); }
  __shared__ float rs[4], rss[4];
  const int w = tid >> 6, lane = tid & 63;
  if (lane == 0) { rs[w] = s; rss[w] = ss; }
  __syncthreads();
  s  = rs[0] + rs[1] + rs[2] + rs[3];
  ss = rss[0] + rss[1] + rss[2] + rss[3];
  const float mean = s * (1.f / CDIM);
  const float var  = ss * (1.f / CDIM) - mean * mean;
  const float rstd = rsqrtf(var + 1e-5f);
  const int c = tid * 2;
  out[(size_t)m * CDIM + c]     = f2bf((v.x - mean) * rstd * g[c]     + b[c]);
  out[(size_t)m * CDIM + c + 1] = f2bf((v.y - mean) * rstd * g[c + 1] + b[c + 1]);
}

// ---------------- flash attention, fp16 MFMA, causal ------------------------
// grid (TLEN/64, BSZ*NHEAD), block 256 (4 waves).
__global__ __launch_bounds__(256) void attn_mfma(const float* __restrict__ qkv,
                                                 ushort_t* __restrict__ ybf) {
  __shared__ ushort_t Ks[32 * 72];      // 4.5 KB
  __shared__ ushort_t Vt[64 * 40];      // 5.0 KB
  __shared__ ushort_t Pl[4 * 16 * 40];  // 5.0 KB (per-wave 16x32 P, stride 40)

  const int tid  = threadIdx.x;
  const int wave = tid >> 6, lane = tid & 63;
  const int lr   = lane & 15;           // fragment row / output col
  const int quad = lane >> 4;
  const int kq   = quad << 3;           // fragment k offset
  const int t0   = blockIdx.x << 6;     // block q base (64 rows)
  const int bh   = blockIdx.y;
  const int bb   = bh >> 3, hh = bh & 7;
  const int qb   = t0 + (wave << 4);    // wave q base (16 rows)
  const size_t RS = 3 * CDIM;           // 1536

  // --- Q fragments: A[q=16][d=64] as 2 chunks of K=32 ---
  half8 aq[2];
  {
    const float* qr = qkv + (size_t)(bb * TLEN + qb + lr) * RS + hh * 64 + kq;
#pragma unroll
    for (int c = 0; c < 2; ++c) {
      float4 f0 = *(const float4*)(qr + c * 32);
      float4 f1 = *(const float4*)(qr + c * 32 + 4);
      half8 v;
      v[0] = (_Float16)f0.x; v[1] = (_Float16)f0.y;
      v[2] = (_Float16)f0.z; v[3] = (_Float16)f0.w;
      v[4] = (_Float16)f1.x; v[5] = (_Float16)f1.y;
      v[6] = (_Float16)f1.z; v[7] = (_Float16)f1.w;
      aq[c] = v;
    }
  }

  f32x4 o[4];
#pragma unroll
  for (int dt = 0; dt < 4; ++dt) { o[dt][0] = 0.f; o[dt][1] = 0.f; o[dt][2] = 0.f; o[dt][3] = 0.f; }
  float m[4] = { -1e30f, -1e30f, -1e30f, -1e30f };
  float l[4] = { 0.f, 0.f, 0.f, 0.f };

  // staging decomposition: thread -> (key kk, d-chunk of 8)
  const int kk    = tid & 31;
  const int dbase = (tid >> 5) << 3;

  const int ntiles = (blockIdx.x + 1) << 1;   // causal: keys 0 .. t0+63
  for (int kb = 0; kb < ntiles; ++kb) {
    const int kbase = kb << 5;
    __syncthreads();   // protect LDS from previous iteration's readers
    {
      const float* kp = qkv + (size_t)(bb * TLEN + kbase + kk) * RS + CDIM + hh * 64 + dbase;
      float4 f0 = *(const float4*)kp;
      float4 f1 = *(const float4*)(kp + 4);
      half8 kv;
      kv[0] = (_Float16)f0.x; kv[1] = (_Float16)f0.y;
      kv[2] = (_Float16)f0.z; kv[3] = (_Float16)f0.w;
      kv[4] = (_Float16)f1.x; kv[5] = (_Float16)f1.y;
      kv[6] = (_Float16)f1.z; kv[7] = (_Float16)f1.w;
      *(half8*)(Ks + kk * 72 + dbase) = kv;
      const float* vp = kp + CDIM;          // V block
      float4 g0 = *(const float4*)vp;
      float4 g1 = *(const float4*)(vp + 4);
      ushort_t vb[8] = { f2h(g0.x), f2h(g0.y), f2h(g0.z), f2h(g0.w),
                         f2h(g1.x), f2h(g1.y), f2h(g1.z), f2h(g1.w) };
#pragma unroll
      for (int j = 0; j < 8; ++j) Vt[(dbase + j) * 40 + kk] = vb[j];  // transpose
    }
    __syncthreads();   // tiles ready

    if (kbase <= qb + 15) {   // wave-uniform causal skip
      // --- S = Q @ K^T : two 16x16 k-sub-tiles ---
      f32x4 st[2];
#pragma unroll
      for (int kt = 0; kt < 2; ++kt) {
        half8 b0 = *(const half8*)(Ks + (kt * 16 + lr) * 72 + kq);
        half8 b1 = *(const half8*)(Ks + (kt * 16 + lr) * 72 + 32 + kq);
        f32x4 acc = { 0.f, 0.f, 0.f, 0.f };
        acc = __builtin_amdgcn_mfma_f32_16x16x32_f16(aq[0], b0, acc, 0, 0, 0);
        acc = __builtin_amdgcn_mfma_f32_16x16x32_f16(aq[1], b1, acc, 0, 0, 0);
        st[kt] = acc;
      }
      // --- scale + causal mask + online softmax ---
      float corr[4];
#pragma unroll
      for (int r = 0; r < 4; ++r) {
        const int qrow = qb + quad * 4 + r;
#pragma unroll
        for (int kt = 0; kt < 2; ++kt) {
          const int kcol = kbase + kt * 16 + lr;
          float s = st[kt][r] * 0.125f;           // 1/sqrt(64)
          st[kt][r] = (kcol <= qrow) ? s : -1e30f;
        }
        float mx = fmaxf(st[0][r], st[1][r]);
#pragma unroll
        for (int off = 8; off; off >>= 1) mx = fmaxf(mx, __shfl_xor(mx, off));
        const float mnew = fmaxf(m[r], mx);
        corr[r] = __expf(m[r] - mnew);
        m[r] = mnew;
        float p0 = __expf(st[0][r] - mnew);
        float p1 = __expf(st[1][r] - mnew);
        st[0][r] = p0; st[1][r] = p1;
        float ps = p0 + p1;
#pragma unroll
        for (int off = 8; off; off >>= 1) ps += __shfl_xor(ps, off);
        l[r] = l[r] * corr[r] + ps;
      }
      // --- rescale O, stash P (fp16) to per-wave LDS, PV MFMA ---
#pragma unroll
      for (int dt = 0; dt < 4; ++dt)
#pragma unroll
        for (int r = 0; r < 4; ++r) o[dt][r] *= corr[r];
      ushort_t* pw = Pl + wave * 640;   // 16 rows x 40
#pragma unroll
      for (int kt = 0; kt < 2; ++kt)
#pragma unroll
        for (int r = 0; r < 4; ++r)
          pw[(quad * 4 + r) * 40 + kt * 16 + lr] = f2h(st[kt][r]);
      half8 ap = *(const half8*)(pw + lr * 40 + kq);   // A[q=16][k=32] fragment
#pragma unroll
      for (int dt = 0; dt < 4; ++dt) {
        half8 bv = *(const half8*)(Vt + (dt * 16 + lr) * 40 + kq);
        o[dt] = __builtin_amdgcn_mfma_f32_16x16x32_f16(ap, bv, o[dt], 0, 0, 0);
      }
    }
  }

  // --- epilogue: normalize, write bf16 directly ---
#pragma unroll
  for (int r = 0; r < 4; ++r) {
    const float inv = 1.0f / l[r];
    const int qrow = qb + quad * 4 + r;
    ushort_t* yp = ybf + (size_t)(bb * TLEN + qrow) * CDIM + hh * 64;
#pragma unroll
    for (int dt = 0; dt < 4; ++dt)
      yp[dt * 16 + lr] = f2bf(o[dt][r] * inv);
  }
}

// ---------------- launch ----------------
extern "C" void kernel_launch(void* const* d_in, const int* in_sizes, int n_in,
                              void* d_out, int out_size, void* d_ws, size_t ws_size,
                              hipStream_t stream) {
  const int*   idx     = (const int*)  d_in[0];
  const float* wte     = (const float*)d_in[1];
  const float* wpe     = (const float*)d_in[2];
  const float* ln1_g   = (const float*)d_in[3];
  const float* ln1_b   = (const float*)d_in[4];
  const float* attn_w  = (const float*)d_in[5];
  const float* attn_lA = (const float*)d_in[6];
  const float* attn_lB = (const float*)d_in[7];
  const float* proj_w  = (const float*)d_in[8];
  const float* proj_lA = (const float*)d_in[9];
  const float* proj_lB = (const float*)d_in[10];
  const float* ln2_g   = (const float*)d_in[11];
  const float* ln2_b   = (const float*)d_in[12];
  const float* fc_w    = (const float*)d_in[13];
  const float* fc_b    = (const float*)d_in[14];
  const float* mproj_w = (const float*)d_in[15];
  const float* mproj_b = (const float*)d_in[16];
  const float* lnf_g   = (const float*)d_in[17];
  const float* lnf_b   = (const float*)d_in[18];
  const float* head_w  = (const float*)d_in[19];
  float* out = (float*)d_out;

  // workspace carve (256B aligned)
  uintptr_t p = (uintptr_t)d_ws;
  auto take = [&](size_t bytes) -> void* {
    uintptr_t q = p;
    p = (p + bytes + 255) & ~(uintptr_t)255;
    return (void*)q;
  };
  ushort_t* wAttnB  = (ushort_t*)take((size_t)NLAYER * 1536 * 512 * 2);
  ushort_t* wProjB  = (ushort_t*)take((size_t)NLAYER * 512 * 512 * 2);
  ushort_t* wFcB    = (ushort_t*)take((size_t)NLAYER * 2048 * 512 * 2);
  ushort_t* wMprojB = (ushort_t*)take((size_t)NLAYER * 512 * 2048 * 2);
  ushort_t* wHeadB  = (ushort_t*)take((size_t)VOCAB * 512 * 2);
  float*    x       = (float*)   take((size_t)MROWS * 512 * 4);
  ushort_t* hbf     = (ushort_t*)take((size_t)MROWS * 512 * 2);
  float*    qkv     = (float*)   take((size_t)MROWS * 1536 * 4);
  ushort_t* ybf     = (ushort_t*)take((size_t)MROWS * 512 * 2);
  ushort_t* mbf     = (ushort_t*)take((size_t)MROWS * 2048 * 2);

  // ---- weight prep (per launch; LoRA folded into qkv/proj weights) ----
  {
    long nA = (long)NLAYER * 1536 * 512;
    conv_lora<<<(int)((nA + 255) / 256), 256, 0, stream>>>(attn_w, attn_lA, attn_lB, wAttnB, 1536, nA);
    long nP = (long)NLAYER * 512 * 512;
    conv_lora<<<(int)((nP + 255) / 256), 256, 0, stream>>>(proj_w, proj_lA, proj_lB, wProjB, 512, nP);
    long nF = (long)NLAYER * 2048 * 512;
    conv_bf16<<<(int)((nF / 4 + 255) / 256), 256, 0, stream>>>(fc_w, wFcB, nF);
    long nM = (long)NLAYER * 512 * 2048;
    conv_bf16<<<(int)((nM / 4 + 255) / 256), 256, 0, stream>>>(mproj_w, wMprojB, nM);
    long nH = (long)VOCAB * 512;
    conv_bf16<<<(int)((nH / 4 + 255) / 256), 256, 0, stream>>>(head_w, wHeadB, nH);
  }

  // ---- embedding ----
  embed_kernel<<<(MROWS * 512) / 256, 256, 0, stream>>>(idx, wte, wpe, x);

  // ---- transformer layers ----
  for (int l = 0; l < NLAYER; ++l) {
    ln_kernel<<<MROWS, 256, 0, stream>>>(x, ln1_g + l * 512, ln1_b + l * 512, hbf);
    gemm_bt<0><<<dim3(1536 / 128, MROWS / 128), 256, 0, stream>>>(
        hbf, wAttnB + (size_t)l * 1536 * 512, qkv, nullptr, MROWS, 1536, 512);
    attn_mfma<<<dim3(TLEN / 64, BSZ * NHEAD), 256, 0, stream>>>(qkv, ybf);
    // proj + residual fused:  x += ybf @ Wproj^T
    gemm64_res<<<dim3(512 / 64, MROWS / 64), 256, 0, stream>>>(
        ybf, wProjB + (size_t)l * 512 * 512, x, nullptr, MROWS, 512, 512);

    ln_kernel<<<MROWS, 256, 0, stream>>>(x, ln2_g + l * 512, ln2_b + l * 512, hbf);
    // fc + bias + gelu fused -> bf16 mbf
    gemm_bt<2><<<dim3(2048 / 128, MROWS / 128), 256, 0, stream>>>(
        hbf, wFcB + (size_t)l * 2048 * 512, mbf, fc_b + l * 2048, MROWS, 2048, 512);
    // mproj + bias + residual fused:  x += mbf @ Wmproj^T + mproj_b
    gemm64_res<<<dim3(512 / 64, MROWS / 64), 256, 0, stream>>>(
        mbf, wMprojB + (size_t)l * 512 * 2048, x, mproj_b + l * 512, MROWS, 512, 2048);
  }

  // ---- final LN + head ----
  ln_kernel<<<MROWS, 256, 0, stream>>>(x, lnf_g, lnf_b, hbf);
  gemm_bt<0><<<dim3((VOCAB + 127) / 128, MROWS / 128), 256, 0, stream>>>(
      hbf, wHeadB, out, nullptr, MROWS, VOCAB, 512);
}

// Round 5
// 1328.338 us; speedup vs baseline: 1.9166x; 1.0067x over previous
//
#include <hip/hip_runtime.h>
#include <cstdint>
#include <cstddef>

// ---------------- problem constants ----------------
#define NLAYER 4
#define CDIM   512
#define TLEN   1024
#define BSZ    2
#define MROWS  (BSZ * TLEN)   // 2048
#define VOCAB  50257
#define NHEAD  8
#define HDIM   64
#define LORA_S 4.0f

typedef unsigned short ushort_t;
typedef __attribute__((ext_vector_type(8))) short  short8;
typedef __attribute__((ext_vector_type(8))) _Float16 half8;
typedef __attribute__((ext_vector_type(4))) float  f32x4;
typedef __attribute__((ext_vector_type(4))) unsigned short us4;

// fp32 -> bf16, round-to-nearest-even (finite inputs only)
__device__ inline ushort_t f2bf(float f) {
  union { float f; unsigned u; } c; c.f = f;
  unsigned u = c.u;
  u += 0x7fffu + ((u >> 16) & 1u);
  return (ushort_t)(u >> 16);
}

// fp32 -> fp16 bits (native v_cvt_f16_f32)
__device__ inline ushort_t f2h(float f) {
  union { _Float16 h; ushort_t u; } c; c.h = (_Float16)f;
  return c.u;
}

__device__ inline float gelu_f(float v) {
  float t = tanhf(0.7978845608028654f * (v + 0.044715f * v * v * v));
  return 0.5f * v * (1.0f + t);
}

// async global->LDS, 16B per lane; lds dest = wave-uniform base + lane*16
__device__ inline void stage16(const ushort_t* g, ushort_t* lds) {
  __builtin_amdgcn_global_load_lds(
      (__attribute__((address_space(1))) unsigned int*)(g),
      (__attribute__((address_space(3))) unsigned int*)(lds),
      16, 0, 0);
}

// bijective XCD-chunk swizzle (m204): blocks round-robin over 8 XCDs; remap so
// each XCD owns a contiguous chunk of logical tile ids -> L2 panel reuse.
__device__ inline int xcd_swz(int flat, int nwg) {
  int q = nwg >> 3, r = nwg & 7;
  int x = flat & 7, pos = flat >> 3;
  return (x < r ? x * (q + 1) : r * (q + 1) + (x - r) * q) + pos;
}

// ---------------- bf16 MFMA GEMM:  C[M,N] = A[M,K] @ B[N,K]^T ----------------
// 128x128 block tile, BK=32, 4 waves each computing a 64x64 subtile (4x4 MFMA).
// 1-D grid = NT_N * NT_M, XCD-chunked, m-fastest inside a chunk (B-panel reuse).
// M multiple of 128; N guarded (head matmul N=50257); K multiple of 32.
// EPI: 0 = plain fp32 store; 2 = bf16 store of gelu(acc + bias[col]).
template<int EPI>
__global__ __launch_bounds__(256) void gemm_bt(const ushort_t* __restrict__ A,
                                               const ushort_t* __restrict__ B,
                                               void* __restrict__ Cv,
                                               const float* __restrict__ bias,
                                               int M, int N, int K) {
  __shared__ ushort_t As[128 * 32];   // 8 KB, row-major [row][k]
  __shared__ ushort_t Bs[128 * 32];   // 8 KB, row-major [n][k]
  const int tid  = threadIdx.x;
  const int wave = tid >> 6, lane = tid & 63;
  const int ntm  = M >> 7;
  const int swz  = xcd_swz(blockIdx.x, gridDim.x);
  const int nid  = swz / ntm;
  const int mid  = swz - nid * ntm;
  const int m0 = mid << 7;
  const int n0 = nid << 7;
  const int wr = (wave >> 1) << 6;    // wave sub-tile row base (0/64)
  const int wc = (wave & 1) << 6;     // wave sub-tile col base (0/64)
  const int lr = lane & 15;           // fragment row
  const int kq = (lane >> 4) << 3;    // fragment k offset (quad*8)

  f32x4 acc[4][4];
#pragma unroll
  for (int i = 0; i < 4; ++i)
#pragma unroll
    for (int j = 0; j < 4; ++j) {
      acc[i][j][0] = 0.f; acc[i][j][1] = 0.f;
      acc[i][j][2] = 0.f; acc[i][j][3] = 0.f;
    }

  for (int k0 = 0; k0 < K; k0 += 32) {
    __syncthreads();   // protect LDS from previous iteration's readers
    // A tile: 128x32 bf16 = 512 chunks of 16B; thread t stages chunks t, t+256
#pragma unroll
    for (int i = 0; i < 2; ++i) {
      int c = i * 256 + tid;
      int row = c >> 2, col = (c & 3) << 3;
      stage16(A + (size_t)(m0 + row) * K + k0 + col,
              As + ((i * 256 + (wave << 6)) << 3));
    }
#pragma unroll
    for (int i = 0; i < 2; ++i) {
      int c = i * 256 + tid;
      int row = c >> 2, col = (c & 3) << 3;
      int n = n0 + row; if (n > N - 1) n = N - 1;   // clamp (head tail tile)
      stage16(B + (size_t)n * K + k0 + col,
              Bs + ((i * 256 + (wave << 6)) << 3));
    }
    __syncthreads();   // drains vmcnt -> LDS tiles ready

    short8 af[4], bf[4];
#pragma unroll
    for (int i = 0; i < 4; ++i)
      af[i] = *(const short8*)(As + (wr + i * 16 + lr) * 32 + kq);
#pragma unroll
    for (int j = 0; j < 4; ++j)
      bf[j] = *(const short8*)(Bs + (wc + j * 16 + lr) * 32 + kq);
#pragma unroll
    for (int i = 0; i < 4; ++i)
#pragma unroll
      for (int j = 0; j < 4; ++j)
        acc[i][j] = __builtin_amdgcn_mfma_f32_16x16x32_bf16(af[i], bf[j], acc[i][j], 0, 0, 0);
  }

  // epilogue: D mapping col=lane&15, row=(lane>>4)*4+reg
  const int rq = (lane >> 4) << 2;
  const int cl = lane & 15;
#pragma unroll
  for (int i = 0; i < 4; ++i) {
    int mb = m0 + wr + i * 16 + rq;
#pragma unroll
    for (int j = 0; j < 4; ++j) {
      int col = n0 + wc + j * 16 + cl;
      if (col < N) {
        if (EPI == 0) {
          float* cp = (float*)Cv + (size_t)mb * N + col;
#pragma unroll
          for (int r = 0; r < 4; ++r) cp[(size_t)r * N] = acc[i][j][r];
        } else {
          ushort_t* cp = (ushort_t*)Cv + (size_t)mb * N + col;
          const float bb = bias[col];
#pragma unroll
          for (int r = 0; r < 4; ++r) cp[(size_t)r * N] = f2bf(gelu_f(acc[i][j][r] + bb));
        }
      }
    }
  }
}

// ---------------- 64x64-tile GEMM with fused residual: x += A@B^T (+bias) ---
// 1-D grid = (N/64)*(M/64), XCD-chunked, m-fastest. 4 waves, 32x32 subtiles.
__global__ __launch_bounds__(256) void gemm64_res(const ushort_t* __restrict__ A,
                                                  const ushort_t* __restrict__ B,
                                                  float* __restrict__ x,
                                                  const float* __restrict__ bias,
                                                  int M, int N, int K) {
  __shared__ ushort_t As[64 * 32];   // 4 KB
  __shared__ ushort_t Bs[64 * 32];   // 4 KB
  const int tid  = threadIdx.x;
  const int wave = tid >> 6, lane = tid & 63;
  const int ntm  = M >> 6;
  const int swz  = xcd_swz(blockIdx.x, gridDim.x);
  const int nid  = swz / ntm;
  const int mid  = swz - nid * ntm;
  const int m0 = mid << 6;
  const int n0 = nid << 6;
  const int wr = (wave >> 1) << 5;    // 0/32
  const int wc = (wave & 1) << 5;     // 0/32
  const int lr = lane & 15;
  const int kq = (lane >> 4) << 3;

  f32x4 acc[2][2];
#pragma unroll
  for (int i = 0; i < 2; ++i)
#pragma unroll
    for (int j = 0; j < 2; ++j) {
      acc[i][j][0] = 0.f; acc[i][j][1] = 0.f;
      acc[i][j][2] = 0.f; acc[i][j][3] = 0.f;
    }

  // staging: 64x32 tile = 256 chunks of 16B; thread t stages chunk t
  const int row = tid >> 2, col = (tid & 3) << 3;

  for (int k0 = 0; k0 < K; k0 += 32) {
    __syncthreads();
    stage16(A + (size_t)(m0 + row) * K + k0 + col, As + (wave << 9));
    stage16(B + (size_t)(n0 + row) * K + k0 + col, Bs + (wave << 9));
    __syncthreads();

    short8 af[2], bf[2];
#pragma unroll
    for (int i = 0; i < 2; ++i)
      af[i] = *(const short8*)(As + (wr + i * 16 + lr) * 32 + kq);
#pragma unroll
    for (int j = 0; j < 2; ++j)
      bf[j] = *(const short8*)(Bs + (wc + j * 16 + lr) * 32 + kq);
#pragma unroll
    for (int i = 0; i < 2; ++i)
#pragma unroll
      for (int j = 0; j < 2; ++j)
        acc[i][j] = __builtin_amdgcn_mfma_f32_16x16x32_bf16(af[i], bf[j], acc[i][j], 0, 0, 0);
  }

  const int rq = (lane >> 4) << 2;
  const int cl = lane & 15;
#pragma unroll
  for (int i = 0; i < 2; ++i) {
    int mb = m0 + wr + i * 16 + rq;
#pragma unroll
    for (int j = 0; j < 2; ++j) {
      int c = n0 + wc + j * 16 + cl;
      float bb = bias ? bias[c] : 0.f;
      float* xp = x + (size_t)mb * N + c;
#pragma unroll
      for (int r = 0; r < 4; ++r) xp[(size_t)r * N] = xp[(size_t)r * N] + acc[i][j][r] + bb;
    }
  }
}

// ---------------- weight prep (merged) ----------------
// LoRA-folded qkv + proj weights in one launch.
__global__ void conv_lora_all(const float* __restrict__ attn_w, const float* __restrict__ attn_lA,
                              const float* __restrict__ attn_lB, const float* __restrict__ proj_w,
                              const float* __restrict__ proj_lA, const float* __restrict__ proj_lB,
                              ushort_t* __restrict__ wAttnB, ushort_t* __restrict__ wProjB) {
  long i = (long)blockIdx.x * 256 + threadIdx.x;
  const long nA = (long)NLAYER * 1536 * CDIM;   // 3145728
  const long nP = (long)NLAYER * 512 * CDIM;    // 1048576
  const float* W; const float* lA; const float* lB; ushort_t* out; int N; long ii;
  if (i < nA) { W = attn_w; lA = attn_lA; lB = attn_lB; out = wAttnB; N = 1536; ii = i; }
  else {
    ii = i - nA; if (ii >= nP) return;
    W = proj_w; lA = proj_lA; lB = proj_lB; out = wProjB; N = 512;
  }
  long nk = (long)N * CDIM;
  int  l  = (int)(ii / nk);
  long r  = ii - (long)l * nk;
  int  n  = (int)(r >> 9);
  int  k  = (int)(r & 511);
  const float* lAp = lA + (long)l * 8 * CDIM;
  const float* lBp = lB + (long)l * N * 8;
  float acc = W[ii];
#pragma unroll
  for (int j = 0; j < 8; ++j) acc += LORA_S * lBp[n * 8 + j] * lAp[j * CDIM + k];
  out[ii] = f2bf(acc);
}

// fc + mproj + head fp32 -> bf16 in one launch (vectorized x4)
__global__ void conv_bf16_all(const float* __restrict__ fc_w, const float* __restrict__ mproj_w,
                              const float* __restrict__ head_w, ushort_t* __restrict__ wFcB,
                              ushort_t* __restrict__ wMprojB, ushort_t* __restrict__ wHeadB) {
  long j = ((long)blockIdx.x * 256 + threadIdx.x) * 4;
  const long nF = (long)NLAYER * 2048 * CDIM;   // 4194304
  const long nM = (long)NLAYER * CDIM * 2048;   // 4194304
  const long nH = (long)VOCAB * CDIM;           // 25731584
  const float* src; ushort_t* dst; long off;
  if (j < nF)           { src = fc_w;    dst = wFcB;    off = j; }
  else if (j < nF + nM) { src = mproj_w; dst = wMprojB; off = j - nF; }
  else if (j < nF + nM + nH) { src = head_w; dst = wHeadB; off = j - nF - nM; }
  else return;
  float4 v = *(const float4*)(src + off);
  us4 o = { f2bf(v.x), f2bf(v.y), f2bf(v.z), f2bf(v.w) };
  *(us4*)(dst + off) = o;
}

// ---------------- embedding (vectorized x4) ----------------
__global__ void embed_kernel(const int* __restrict__ idx, const float* __restrict__ wte,
                             const float* __restrict__ wpe, float* __restrict__ x) {
  int i = (blockIdx.x * 256 + threadIdx.x) * 4;  // over MROWS*CDIM = 1M
  int m = i >> 9, c = i & 511;
  int t = m & (TLEN - 1);
  float4 a = *(const float4*)(wte + (size_t)idx[m] * CDIM + c);
  float4 b = *(const float4*)(wpe + (size_t)t * CDIM + c);
  float4 o = { a.x + b.x, a.y + b.y, a.z + b.z, a.w + b.w };
  *(float4*)(x + i) = o;
}

// ---------------- layernorm (fp32 in, bf16 out), one row per block ----------
__global__ __launch_bounds__(256) void ln_kernel(const float* __restrict__ x,
                                                 const float* __restrict__ g,
                                                 const float* __restrict__ b,
                                                 ushort_t* __restrict__ out) {
  const int m = blockIdx.x, tid = threadIdx.x;
  const float2 v = ((const float2*)(x + (size_t)m * CDIM))[tid];
  float s = v.x + v.y, ss = v.x * v.x + v.y * v.y;
#pragma unroll
  for (int off = 32; off; off >>= 1) { s += __shfl_xor(s, off); ss += __shfl_xor(ss, off); }
  __shared__ float rs[4], rss[4];
  const int w = tid >> 6, lane = tid & 63;
  if (lane == 0) { rs[w] = s; rss[w] = ss; }
  __syncthreads();
  s  = rs[0] + rs[1] + rs[2] + rs[3];
  ss = rss[0] + rss[1] + rss[2] + rss[3];
  const float mean = s * (1.f / CDIM);
  const float var  = ss * (1.f / CDIM) - mean * mean;
  const float rstd = rsqrtf(var + 1e-5f);
  const int c = tid * 2;
  out[(size_t)m * CDIM + c]     = f2bf((v.x - mean) * rstd * g[c]     + b[c]);
  out[(size_t)m * CDIM + c + 1] = f2bf((v.y - mean) * rstd * g[c + 1] + b[c + 1]);
}

// ---------------- flash attention, fp16 MFMA, causal (R2-proven version) ----
// grid (TLEN/64, BSZ*NHEAD), block 256 (4 waves).
// Each wave owns 16 q rows (one 16x16x32 A-fragment set, Q in registers).
// K-loop over 32-key tiles staged in LDS by all 4 waves:
//   K row-major [32][72 pad], V transposed [64][40 pad].
// Online softmax in fragment layout; P round-trips per-wave LDS buffer.
__global__ __launch_bounds__(256) void attn_mfma(const float* __restrict__ qkv,
                                                 ushort_t* __restrict__ ybf) {
  __shared__ ushort_t Ks[32 * 72];      // 4.5 KB
  __shared__ ushort_t Vt[64 * 40];      // 5.0 KB
  __shared__ ushort_t Pl[4 * 16 * 40];  // 5.0 KB (per-wave 16x32 P, stride 40)

  const int tid  = threadIdx.x;
  const int wave = tid >> 6, lane = tid & 63;
  const int lr   = lane & 15;           // fragment row / output col
  const int quad = lane >> 4;
  const int kq   = quad << 3;           // fragment k offset
  const int t0   = blockIdx.x << 6;     // block q base (64 rows)
  const int bh   = blockIdx.y;
  const int bb   = bh >> 3, hh = bh & 7;
  const int qb   = t0 + (wave << 4);    // wave q base (16 rows)
  const size_t RS = 3 * CDIM;           // 1536

  // --- Q fragments: A[q=16][d=64] as 2 chunks of K=32 ---
  half8 aq[2];
  {
    const float* qr = qkv + (size_t)(bb * TLEN + qb + lr) * RS + hh * 64 + kq;
#pragma unroll
    for (int c = 0; c < 2; ++c) {
      float4 f0 = *(const float4*)(qr + c * 32);
      float4 f1 = *(const float4*)(qr + c * 32 + 4);
      half8 v;
      v[0] = (_Float16)f0.x; v[1] = (_Float16)f0.y;
      v[2] = (_Float16)f0.z; v[3] = (_Float16)f0.w;
      v[4] = (_Float16)f1.x; v[5] = (_Float16)f1.y;
      v[6] = (_Float16)f1.z; v[7] = (_Float16)f1.w;
      aq[c] = v;
    }
  }

  f32x4 o[4];
#pragma unroll
  for (int dt = 0; dt < 4; ++dt) { o[dt][0] = 0.f; o[dt][1] = 0.f; o[dt][2] = 0.f; o[dt][3] = 0.f; }
  float m[4] = { -1e30f, -1e30f, -1e30f, -1e30f };
  float l[4] = { 0.f, 0.f, 0.f, 0.f };

  // staging decomposition: thread -> (key kk, d-chunk of 8)
  const int kk    = tid & 31;
  const int dbase = (tid >> 5) << 3;

  const int ntiles = (blockIdx.x + 1) << 1;   // causal: keys 0 .. t0+63
  for (int kb = 0; kb < ntiles; ++kb) {
    const int kbase = kb << 5;
    __syncthreads();   // protect LDS from previous iteration's readers
    {
      const float* kp = qkv + (size_t)(bb * TLEN + kbase + kk) * RS + CDIM + hh * 64 + dbase;
      float4 f0 = *(const float4*)kp;
      float4 f1 = *(const float4*)(kp + 4);
      half8 kv;
      kv[0] = (_Float16)f0.x; kv[1] = (_Float16)f0.y;
      kv[2] = (_Float16)f0.z; kv[3] = (_Float16)f0.w;
      kv[4] = (_Float16)f1.x; kv[5] = (_Float16)f1.y;
      kv[6] = (_Float16)f1.z; kv[7] = (_Float16)f1.w;
      *(half8*)(Ks + kk * 72 + dbase) = kv;
      const float* vp = kp + CDIM;          // V block
      float4 g0 = *(const float4*)vp;
      float4 g1 = *(const float4*)(vp + 4);
      ushort_t vb[8] = { f2h(g0.x), f2h(g0.y), f2h(g0.z), f2h(g0.w),
                         f2h(g1.x), f2h(g1.y), f2h(g1.z), f2h(g1.w) };
#pragma unroll
      for (int j = 0; j < 8; ++j) Vt[(dbase + j) * 40 + kk] = vb[j];  // transpose
    }
    __syncthreads();   // tiles ready

    if (kbase <= qb + 15) {   // wave-uniform causal skip
      // --- S = Q @ K^T : two 16x16 k-sub-tiles ---
      f32x4 st[2];
#pragma unroll
      for (int kt = 0; kt < 2; ++kt) {
        half8 b0 = *(const half8*)(Ks + (kt * 16 + lr) * 72 + kq);
        half8 b1 = *(const half8*)(Ks + (kt * 16 + lr) * 72 + 32 + kq);
        f32x4 acc = { 0.f, 0.f, 0.f, 0.f };
        acc = __builtin_amdgcn_mfma_f32_16x16x32_f16(aq[0], b0, acc, 0, 0, 0);
        acc = __builtin_amdgcn_mfma_f32_16x16x32_f16(aq[1], b1, acc, 0, 0, 0);
        st[kt] = acc;
      }
      // --- scale + causal mask + online softmax ---
      float corr[4];
#pragma unroll
      for (int r = 0; r < 4; ++r) {
        const int qrow = qb + quad * 4 + r;
#pragma unroll
        for (int kt = 0; kt < 2; ++kt) {
          const int kcol = kbase + kt * 16 + lr;
          float s = st[kt][r] * 0.125f;           // 1/sqrt(64)
          st[kt][r] = (kcol <= qrow) ? s : -1e30f;
        }
        float mx = fmaxf(st[0][r], st[1][r]);
#pragma unroll
        for (int off = 8; off; off >>= 1) mx = fmaxf(mx, __shfl_xor(mx, off));
        const float mnew = fmaxf(m[r], mx);
        corr[r] = __expf(m[r] - mnew);
        m[r] = mnew;
        float p0 = __expf(st[0][r] - mnew);
        float p1 = __expf(st[1][r] - mnew);
        st[0][r] = p0; st[1][r] = p1;
        float ps = p0 + p1;
#pragma unroll
        for (int off = 8; off; off >>= 1) ps += __shfl_xor(ps, off);
        l[r] = l[r] * corr[r] + ps;
      }
      // --- rescale O, stash P (fp16) to per-wave LDS, PV MFMA ---
#pragma unroll
      for (int dt = 0; dt < 4; ++dt)
#pragma unroll
        for (int r = 0; r < 4; ++r) o[dt][r] *= corr[r];
      ushort_t* pw = Pl + wave * 640;   // 16 rows x 40
#pragma unroll
      for (int kt = 0; kt < 2; ++kt)
#pragma unroll
        for (int r = 0; r < 4; ++r)
          pw[(quad * 4 + r) * 40 + kt * 16 + lr] = f2h(st[kt][r]);
      half8 ap = *(const half8*)(pw + lr * 40 + kq);   // A[q=16][k=32] fragment
#pragma unroll
      for (int dt = 0; dt < 4; ++dt) {
        half8 bv = *(const half8*)(Vt + (dt * 16 + lr) * 40 + kq);
        o[dt] = __builtin_amdgcn_mfma_f32_16x16x32_f16(ap, bv, o[dt], 0, 0, 0);
      }
    }
  }

  // --- epilogue: normalize, write bf16 directly ---
#pragma unroll
  for (int r = 0; r < 4; ++r) {
    const float inv = 1.0f / l[r];
    const int qrow = qb + quad * 4 + r;
    ushort_t* yp = ybf + (size_t)(bb * TLEN + qrow) * CDIM + hh * 64;
#pragma unroll
    for (int dt = 0; dt < 4; ++dt)
      yp[dt * 16 + lr] = f2bf(o[dt][r] * inv);
  }
}

// ---------------- launch ----------------
extern "C" void kernel_launch(void* const* d_in, const int* in_sizes, int n_in,
                              void* d_out, int out_size, void* d_ws, size_t ws_size,
                              hipStream_t stream) {
  const int*   idx     = (const int*)  d_in[0];
  const float* wte     = (const float*)d_in[1];
  const float* wpe     = (const float*)d_in[2];
  const float* ln1_g   = (const float*)d_in[3];
  const float* ln1_b   = (const float*)d_in[4];
  const float* attn_w  = (const float*)d_in[5];
  const float* attn_lA = (const float*)d_in[6];
  const float* attn_lB = (const float*)d_in[7];
  const float* proj_w  = (const float*)d_in[8];
  const float* proj_lA = (const float*)d_in[9];
  const float* proj_lB = (const float*)d_in[10];
  const float* ln2_g   = (const float*)d_in[11];
  const float* ln2_b   = (const float*)d_in[12];
  const float* fc_w    = (const float*)d_in[13];
  const float* fc_b    = (const float*)d_in[14];
  const float* mproj_w = (const float*)d_in[15];
  const float* mproj_b = (const float*)d_in[16];
  const float* lnf_g   = (const float*)d_in[17];
  const float* lnf_b   = (const float*)d_in[18];
  const float* head_w  = (const float*)d_in[19];
  float* out = (float*)d_out;

  // workspace carve (256B aligned)
  uintptr_t p = (uintptr_t)d_ws;
  auto take = [&](size_t bytes) -> void* {
    uintptr_t q = p;
    p = (p + bytes + 255) & ~(uintptr_t)255;
    return (void*)q;
  };
  ushort_t* wAttnB  = (ushort_t*)take((size_t)NLAYER * 1536 * 512 * 2);
  ushort_t* wProjB  = (ushort_t*)take((size_t)NLAYER * 512 * 512 * 2);
  ushort_t* wFcB    = (ushort_t*)take((size_t)NLAYER * 2048 * 512 * 2);
  ushort_t* wMprojB = (ushort_t*)take((size_t)NLAYER * 512 * 2048 * 2);
  ushort_t* wHeadB  = (ushort_t*)take((size_t)VOCAB * 512 * 2);
  float*    x       = (float*)   take((size_t)MROWS * 512 * 4);
  ushort_t* hbf     = (ushort_t*)take((size_t)MROWS * 512 * 2);
  float*    qkv     = (float*)   take((size_t)MROWS * 1536 * 4);
  ushort_t* ybf     = (ushort_t*)take((size_t)MROWS * 512 * 2);
  ushort_t* mbf     = (ushort_t*)take((size_t)MROWS * 2048 * 2);

  // ---- weight prep (merged; LoRA folded into qkv/proj weights) ----
  conv_lora_all<<<16384, 256, 0, stream>>>(attn_w, attn_lA, attn_lB,
                                           proj_w, proj_lA, proj_lB, wAttnB, wProjB);
  conv_bf16_all<<<33321, 256, 0, stream>>>(fc_w, mproj_w, head_w, wFcB, wMprojB, wHeadB);

  // ---- embedding ----
  embed_kernel<<<(MROWS * 512 / 4) / 256, 256, 0, stream>>>(idx, wte, wpe, x);

  // ---- transformer layers ----
  for (int l = 0; l < NLAYER; ++l) {
    ln_kernel<<<MROWS, 256, 0, stream>>>(x, ln1_g + l * 512, ln1_b + l * 512, hbf);
    gemm_bt<0><<<(1536 / 128) * (MROWS / 128), 256, 0, stream>>>(
        hbf, wAttnB + (size_t)l * 1536 * 512, qkv, nullptr, MROWS, 1536, 512);
    attn_mfma<<<dim3(TLEN / 64, BSZ * NHEAD), 256, 0, stream>>>(qkv, ybf);
    // proj + residual fused:  x += ybf @ Wproj^T
    gemm64_res<<<(512 / 64) * (MROWS / 64), 256, 0, stream>>>(
        ybf, wProjB + (size_t)l * 512 * 512, x, nullptr, MROWS, 512, 512);

    ln_kernel<<<MROWS, 256, 0, stream>>>(x, ln2_g + l * 512, ln2_b + l * 512, hbf);
    // fc + bias + gelu fused -> bf16 mbf
    gemm_bt<2><<<(2048 / 128) * (MROWS / 128), 256, 0, stream>>>(
        hbf, wFcB + (size_t)l * 2048 * 512, mbf, fc_b + l * 2048, MROWS, 2048, 512);
    // mproj + bias + residual fused:  x += mbf @ Wmproj^T + mproj_b
    gemm64_res<<<(512 / 64) * (MROWS / 64), 256, 0, stream>>>(
        mbf, wMprojB + (size_t)l * 512 * 2048, x, mproj_b + l * 512, MROWS, 512, 2048);
  }

  // ---- final LN + head ----
  ln_kernel<<<MROWS, 256, 0, stream>>>(x, lnf_g, lnf_b, hbf);
  gemm_bt<0><<<((VOCAB + 127) / 128) * (MROWS / 128), 256, 0, stream>>>(
      hbf, wHeadB, out, nullptr, MROWS, VOCAB, 512);
}